// Round 5
// baseline (609.562 us; speedup 1.0000x reference)
//
#include <hip/hip_runtime.h>

#define BEV_H 512
#define BEV_W 512
#define BEV_HW (BEV_H * BEV_W)
#define NB 8
#define NP 30000
#define NC 64

// Native clang vector types — required by __builtin_nontemporal_load/store
// (HIP_vector_type float4/int4 are classes and are rejected).
typedef float vfloat4 __attribute__((ext_vector_type(4)));
typedef int   vint4   __attribute__((ext_vector_type(4)));
typedef int   vint2   __attribute__((ext_vector_type(2)));

// Phase 2: record, per BEV cell, the highest pillar index p that maps to it.
// Matches reference "last write wins" (highest p) — absmax 0.0 since R1.
__global__ void scatter_winner_kernel(const int* __restrict__ coords,
                                      int* __restrict__ winner) {
    int idx = blockIdx.x * blockDim.x + threadIdx.x;   // over NB*NP
    if (idx >= NB * NP) return;
    int b = idx / NP;
    int p = idx - b * NP;
    vint2 c2 = __builtin_nontemporal_load((const vint2*)coords + idx);
    int gx = c2.x;
    int gy = c2.y;
    if (gx >= 0 && gx < BEV_W && gy >= 0 && gy < BEV_H) {
        atomicMax(&winner[b * BEV_HW + gy * BEV_W + gx], p);
    }
}

// Phase 3: register-transpose gather (R3 structure — reads and writes both
// ideally coalesced) + non-temporal hints:
//  - out is write-once/never-read  -> nt stores (bypass L2 write-allocate)
//  - feat bytes are read exactly once across the grid -> nt loads
//  - winner stays cached (re-read x4 per tile by the 4 channel-quarters)
__global__ void __launch_bounds__(256)
gather_out_kernel(const float* __restrict__ feat,
                  const int* __restrict__ winner,
                  float* __restrict__ out) {
    int b  = blockIdx.y;
    int t  = threadIdx.x;
    int cg = t & 63;            // cell group of 4
    int cq = t >> 6;            // channel quarter (16 channels)
    int cell0 = blockIdx.x * 256 + 4 * cg;

    const vint4 w4 = *(const vint4*)(winner + b * BEV_HW + cell0);
    const int w[4] = {w4.x, w4.y, w4.z, w4.w};

    const float* fb = feat + (size_t)b * NP * NC + 16 * cq;

    vfloat4 q[4][4];            // [cell][float4-within-quarter]
    #pragma unroll
    for (int j = 0; j < 4; ++j) {
        if (w[j] >= 0) {
            const vfloat4* row = (const vfloat4*)(fb + (size_t)w[j] * NC);
            q[j][0] = __builtin_nontemporal_load(row + 0);
            q[j][1] = __builtin_nontemporal_load(row + 1);
            q[j][2] = __builtin_nontemporal_load(row + 2);
            q[j][3] = __builtin_nontemporal_load(row + 3);
        } else {
            #pragma unroll
            for (int i = 0; i < 4; ++i) q[j][i] = (vfloat4)(0.0f);
        }
    }

    float* o = out + ((size_t)b * NC + 16 * cq) * BEV_HW + cell0;
    #pragma unroll
    for (int i = 0; i < 16; ++i) {
        vfloat4 v;
        v.x = q[0][i >> 2][i & 3];
        v.y = q[1][i >> 2][i & 3];
        v.z = q[2][i >> 2][i & 3];
        v.w = q[3][i >> 2][i & 3];
        __builtin_nontemporal_store(v, (vfloat4*)(o + (size_t)i * BEV_HW));
    }
}

extern "C" void kernel_launch(void* const* d_in, const int* in_sizes, int n_in,
                              void* d_out, int out_size, void* d_ws, size_t ws_size,
                              hipStream_t stream) {
    const float* feat   = (const float*)d_in[0];   // (8, 30000, 64) f32
    const int*   coords = (const int*)d_in[1];     // (8, 30000, 2) i32
    float*       out    = (float*)d_out;           // (8, 64, 512, 512) f32
    int*         winner = (int*)d_ws;              // NB*BEV_HW ints = 8 MB

    // Phase 1: winner = -1 everywhere (0xFF bytes). Capturable memset node.
    (void)hipMemsetAsync(winner, 0xFF, (size_t)NB * BEV_HW * sizeof(int), stream);

    // Phase 2: atomicMax scatter of pillar indices.
    {
        int total = NB * NP;
        int block = 256;
        int grid  = (total + block - 1) / block;
        scatter_winner_kernel<<<grid, block, 0, stream>>>(coords, winner);
    }

    // Phase 3: register-transpose gather with non-temporal loads/stores.
    {
        dim3 block(256, 1, 1);
        dim3 grid(BEV_HW / 256, NB, 1);            // (1024, 8)
        gather_out_kernel<<<grid, block, 0, stream>>>(feat, winner, out);
    }
}